// Round 1
// baseline (705.207 us; speedup 1.0000x reference)
//
#include <hip/hip_runtime.h>
#include <hip/hip_bf16.h>
#include <cmath>

#define BT 8192      // B*T tokens
#define DD 1024      // model dim
#define EE 8         // experts
#define HH 2048      // hidden

typedef __attribute__((ext_vector_type(8))) short bf16x8;
typedef __attribute__((ext_vector_type(4))) float f32x4;

__device__ __forceinline__ unsigned short f2bf(float f) {
    union { float f; unsigned u; } v; v.f = f;
    unsigned r = v.u + 0x7FFFu + ((v.u >> 16) & 1u);   // RNE
    return (unsigned short)(r >> 16);
}

// ---------------- gating: logits, unimix softmax, top-2, renorm ----------------
__global__ void gating_kernel(const float* __restrict__ x, const float* __restrict__ Wg,
                              const float* __restrict__ bg, int* __restrict__ counts,
                              int* __restrict__ tok_list, float* __restrict__ wt_list,
                              float* __restrict__ ssq) {
    int lane = threadIdx.x & 63;
    int wid  = threadIdx.x >> 6;
    int t = blockIdx.x * 4 + wid;           // one wave per token
    const float* xr = x + (size_t)t * DD;
    float acc[EE];
#pragma unroll
    for (int e = 0; e < EE; ++e) acc[e] = 0.f;
    for (int d = lane; d < DD; d += 64) {
        float xv = xr[d];
        const float* wr = Wg + d * EE;
#pragma unroll
        for (int e = 0; e < EE; ++e) acc[e] += xv * wr[e];
    }
#pragma unroll
    for (int off = 32; off; off >>= 1)
#pragma unroll
        for (int e = 0; e < EE; ++e) acc[e] += __shfl_xor(acc[e], off, 64);

    if (lane == 0) {
        float p[EE]; float m = -1e30f;
#pragma unroll
        for (int e = 0; e < EE; ++e) { p[e] = acc[e] + bg[e]; m = fmaxf(m, p[e]); }
        float s = 0.f;
#pragma unroll
        for (int e = 0; e < EE; ++e) { p[e] = expf(p[e] - m); s += p[e]; }
        float inv = 1.f / s, q = 0.f;
#pragma unroll
        for (int e = 0; e < EE; ++e) { p[e] = 0.99f * p[e] * inv + 0.00125f; q += p[e] * p[e]; }
        ssq[t] = q;
        int i1 = 0;
#pragma unroll
        for (int e = 1; e < EE; ++e) if (p[e] > p[i1]) i1 = e;    // lowest idx on tie
        int i2 = (i1 == 0) ? 1 : 0;
#pragma unroll
        for (int e = 0; e < EE; ++e) if (e != i1 && p[e] > p[i2]) i2 = e;
        float sw = p[i1] + p[i2];
        float w1 = p[i1] / sw, w2 = p[i2] / sw;
        int pos1 = atomicAdd(&counts[i1], 1);
        tok_list[i1 * BT + pos1] = t; wt_list[i1 * BT + pos1] = w1;
        int pos2 = atomicAdd(&counts[i2], 1);
        tok_list[i2 * BT + pos2] = t; wt_list[i2 * BT + pos2] = w2;
    }
}

__global__ void offsets_kernel(const int* __restrict__ counts, int* __restrict__ offs) {
    if (threadIdx.x == 0) {
        int a = 0;
        for (int e = 0; e < EE; ++e) { offs[e] = a; a += counts[e]; }
        offs[EE] = a;
    }
}

// ---------------- GEMM1: h = gelu(x_gathered @ W1[e] + b1[e]) -> bf16 hbuf ----------------
__global__ __launch_bounds__(256) void gemm1_kernel(
        const float* __restrict__ x, const float* __restrict__ W1, const float* __restrict__ b1,
        const int* __restrict__ counts, const int* __restrict__ offs,
        const int* __restrict__ tok_list, unsigned short* __restrict__ hbuf) {
    int e   = blockIdx.z;
    int cnt = counts[e];
    int m0  = blockIdx.y * 128;
    if (m0 >= cnt) return;
    int h0   = blockIdx.x * 128;
    int base = offs[e];

    __shared__ __align__(16) unsigned short As[128 * 40];   // [row][k] pad 40
    __shared__ __align__(16) unsigned short Bs[128 * 40];   // [n=h][k] pad 40

    int tid = threadIdx.x, lane = tid & 63, wid = tid >> 6;
    int wr = wid >> 1, wc = wid & 1;

    // A staging map: 2 threads per row, 16 k each
    int arow = tid >> 1, ahalf = tid & 1;
    int rowg = m0 + arow;
    int tokA = tok_list[e * BT + (rowg < cnt ? rowg : m0)];
    const float* xA = x + (size_t)tokA * DD + ahalf * 16;
    // B staging map: thread owns one h (bn), 16 k values (strided global, coalesced across lanes)
    int bn  = tid & 127;
    int bk0 = (tid >> 7) * 16;
    const float* w1p = W1 + (size_t)e * DD * HH + (size_t)(h0 + bn);

    f32x4 acc[4][4];
#pragma unroll
    for (int i = 0; i < 4; ++i)
#pragma unroll
        for (int j = 0; j < 4; ++j) acc[i][j] = (f32x4){0.f, 0.f, 0.f, 0.f};

    for (int ks = 0; ks < DD / 32; ++ks) {
        int k0 = ks * 32;
        __syncthreads();
        // A: fp32 -> bf16
#pragma unroll
        for (int j = 0; j < 4; ++j) {
            float4 v = *reinterpret_cast<const float4*>(xA + k0 + j * 4);
            ushort4 sv = { f2bf(v.x), f2bf(v.y), f2bf(v.z), f2bf(v.w) };
            *reinterpret_cast<ushort4*>(&As[arow * 40 + ahalf * 16 + j * 4]) = sv;
        }
        // B: W1[d][h], per-lane k-strided loads (coalesced across lanes), transpose into [h][k]
        __align__(16) unsigned short breg[16];
#pragma unroll
        for (int kk = 0; kk < 16; ++kk)
            breg[kk] = f2bf(w1p[(size_t)(k0 + bk0 + kk) * HH]);
#pragma unroll
        for (int i = 0; i < 2; ++i)
            *reinterpret_cast<ulonglong2*>(&Bs[bn * 40 + bk0 + i * 8]) =
                *reinterpret_cast<const ulonglong2*>(&breg[i * 8]);
        __syncthreads();

        bf16x8 af[4], bfr[4];
#pragma unroll
        for (int fm = 0; fm < 4; ++fm)
            af[fm] = *reinterpret_cast<const bf16x8*>(&As[(wr * 64 + fm * 16 + (lane & 15)) * 40 + (lane >> 4) * 8]);
#pragma unroll
        for (int fn = 0; fn < 4; ++fn)
            bfr[fn] = *reinterpret_cast<const bf16x8*>(&Bs[(wc * 64 + fn * 16 + (lane & 15)) * 40 + (lane >> 4) * 8]);
#pragma unroll
        for (int fm = 0; fm < 4; ++fm)
#pragma unroll
            for (int fn = 0; fn < 4; ++fn)
                acc[fm][fn] = __builtin_amdgcn_mfma_f32_16x16x32_bf16(af[fm], bfr[fn], acc[fm][fn], 0, 0, 0);
    }

    const float* b1e = b1 + e * HH;
#pragma unroll
    for (int fm = 0; fm < 4; ++fm) {
#pragma unroll
        for (int j = 0; j < 4; ++j) {
            int r = m0 + wr * 64 + fm * 16 + (lane >> 4) * 4 + j;
            if (r >= cnt) continue;
            size_t rb = (size_t)(base + r) * HH;
#pragma unroll
            for (int fn = 0; fn < 4; ++fn) {
                int h = h0 + wc * 64 + fn * 16 + (lane & 15);
                float v = acc[fm][fn][j] + b1e[h];
                v = 0.5f * v * (1.f + erff(v * 0.70710678118654752f));   // exact gelu
                hbuf[rb + h] = f2bf(v);
            }
        }
    }
}

// ---------------- GEMM2: out += w * (h @ W2[e] + b2[e]) ----------------
__global__ __launch_bounds__(256) void gemm2_kernel(
        const unsigned short* __restrict__ hbuf, const float* __restrict__ W2,
        const float* __restrict__ b2, const int* __restrict__ counts, const int* __restrict__ offs,
        const int* __restrict__ tok_list, const float* __restrict__ wt_list,
        float* __restrict__ out) {
    int e   = blockIdx.z;
    int cnt = counts[e];
    int m0  = blockIdx.y * 128;
    if (m0 >= cnt) return;
    int d0   = blockIdx.x * 128;
    int base = offs[e];

    __shared__ __align__(16) unsigned short As[128 * 40];
    __shared__ __align__(16) unsigned short Bs[128 * 40];

    int tid = threadIdx.x, lane = tid & 63, wid = tid >> 6;
    int wr = wid >> 1, wc = wid & 1;

    int arow = tid >> 1, ahalf = tid & 1;
    int rowg = m0 + arow;
    int rcl  = rowg < cnt ? rowg : m0;
    const unsigned short* hA = hbuf + (size_t)(base + rcl) * HH + ahalf * 16;
    int bn  = tid & 127;
    int bk0 = (tid >> 7) * 16;
    const float* w2p = W2 + (size_t)e * HH * DD + (size_t)(d0 + bn);

    f32x4 acc[4][4];
#pragma unroll
    for (int i = 0; i < 4; ++i)
#pragma unroll
        for (int j = 0; j < 4; ++j) acc[i][j] = (f32x4){0.f, 0.f, 0.f, 0.f};

    for (int ks = 0; ks < HH / 32; ++ks) {
        int k0 = ks * 32;
        __syncthreads();
#pragma unroll
        for (int i = 0; i < 2; ++i) {
            ulonglong2 v = *reinterpret_cast<const ulonglong2*>(hA + k0 + i * 8);
            *reinterpret_cast<ulonglong2*>(&As[arow * 40 + ahalf * 16 + i * 8]) = v;
        }
        __align__(16) unsigned short breg[16];
#pragma unroll
        for (int kk = 0; kk < 16; ++kk)
            breg[kk] = f2bf(w2p[(size_t)(k0 + bk0 + kk) * DD]);
#pragma unroll
        for (int i = 0; i < 2; ++i)
            *reinterpret_cast<ulonglong2*>(&Bs[bn * 40 + bk0 + i * 8]) =
                *reinterpret_cast<const ulonglong2*>(&breg[i * 8]);
        __syncthreads();

        bf16x8 af[4], bfr[4];
#pragma unroll
        for (int fm = 0; fm < 4; ++fm)
            af[fm] = *reinterpret_cast<const bf16x8*>(&As[(wr * 64 + fm * 16 + (lane & 15)) * 40 + (lane >> 4) * 8]);
#pragma unroll
        for (int fn = 0; fn < 4; ++fn)
            bfr[fn] = *reinterpret_cast<const bf16x8*>(&Bs[(wc * 64 + fn * 16 + (lane & 15)) * 40 + (lane >> 4) * 8]);
#pragma unroll
        for (int fm = 0; fm < 4; ++fm)
#pragma unroll
            for (int fn = 0; fn < 4; ++fn)
                acc[fm][fn] = __builtin_amdgcn_mfma_f32_16x16x32_bf16(af[fm], bfr[fn], acc[fm][fn], 0, 0, 0);
    }

    const float* b2e = b2 + e * DD;
#pragma unroll
    for (int fm = 0; fm < 4; ++fm) {
#pragma unroll
        for (int j = 0; j < 4; ++j) {
            int r = m0 + wr * 64 + fm * 16 + (lane >> 4) * 4 + j;
            if (r >= cnt) continue;
            int token = tok_list[e * BT + r];
            float w   = wt_list[e * BT + r];
            float* orow = out + (size_t)token * DD;
#pragma unroll
            for (int fn = 0; fn < 4; ++fn) {
                int d = d0 + wc * 64 + fn * 16 + (lane & 15);
                float v = acc[fm][fn][j] + b2e[d];
                atomicAdd(&orow[d], w * v);   // exactly 2 adds/elem, commutative -> deterministic
            }
        }
    }
}

// ---------------- aux = mean(sum probs^2) * E ----------------
__global__ void aux_kernel(const float* __restrict__ ssq, float* __restrict__ out_aux) {
    __shared__ float red[4];
    float s = 0.f;
    for (int i = threadIdx.x; i < BT; i += 256) s += ssq[i];
#pragma unroll
    for (int off = 32; off; off >>= 1) s += __shfl_xor(s, off, 64);
    if ((threadIdx.x & 63) == 0) red[threadIdx.x >> 6] = s;
    __syncthreads();
    if (threadIdx.x == 0)
        out_aux[0] = (red[0] + red[1] + red[2] + red[3]) * (float)EE / (float)BT;
}

extern "C" void kernel_launch(void* const* d_in, const int* in_sizes, int n_in,
                              void* d_out, int out_size, void* d_ws, size_t ws_size,
                              hipStream_t stream) {
    const float* x  = (const float*)d_in[0];
    const float* Wg = (const float*)d_in[1];
    const float* bg = (const float*)d_in[2];
    const float* W1 = (const float*)d_in[3];
    const float* b1 = (const float*)d_in[4];
    const float* W2 = (const float*)d_in[5];
    const float* b2 = (const float*)d_in[6];
    float* out = (float*)d_out;

    char* wsb = (char*)d_ws;
    int*   counts = (int*)wsb;                       // 8 ints
    int*   offs   = (int*)(wsb + 64);                // 9 ints
    int*   tok    = (int*)(wsb + 256);               // 8*8192 ints
    float* wts    = (float*)(wsb + 262400);          // 8*8192 floats
    float* ssq    = (float*)(wsb + 524544);          // 8192 floats
    unsigned short* hbuf = (unsigned short*)(wsb + 557312);  // 16384*2048 bf16 = 67MB

    hipMemsetAsync(wsb, 0, 64, stream);                                  // counts
    hipMemsetAsync(out, 0, (size_t)BT * DD * sizeof(float), stream);     // out accumulator

    gating_kernel<<<BT / 4, 256, 0, stream>>>(x, Wg, bg, counts, tok, wts, ssq);
    offsets_kernel<<<1, 64, 0, stream>>>(counts, offs);
    gemm1_kernel<<<dim3(HH / 128, BT / 128, EE), 256, 0, stream>>>(x, W1, b1, counts, offs, tok, hbuf);
    gemm2_kernel<<<dim3(DD / 128, BT / 128, EE), 256, 0, stream>>>(hbuf, W2, b2, counts, offs, tok, wts, out);
    aux_kernel<<<1, 256, 0, stream>>>(ssq, out + (size_t)BT * DD);
}

// Round 2
// 580.216 us; speedup vs baseline: 1.2154x; 1.2154x over previous
//
#include <hip/hip_runtime.h>
#include <hip/hip_bf16.h>
#include <cmath>

#define BT 8192      // B*T tokens
#define DD 1024      // model dim
#define EE 8         // experts
#define HH 2048      // hidden

typedef __attribute__((ext_vector_type(8))) short bf16x8;
typedef __attribute__((ext_vector_type(4))) float f32x4;

__device__ __forceinline__ unsigned short f2bf(float f) {
    union { float f; unsigned u; } v; v.f = f;
    unsigned r = v.u + 0x7FFFu + ((v.u >> 16) & 1u);   // RNE
    return (unsigned short)(r >> 16);
}

// async global->LDS, 16B per lane; LDS dest = wave-uniform base + lane*16
__device__ __forceinline__ void gload16(const void* g, void* l) {
    __builtin_amdgcn_global_load_lds(
        (const __attribute__((address_space(1))) void*)g,
        (__attribute__((address_space(3))) void*)l, 16, 0, 0);
}

// ---------------- prepass: x fp32 -> bf16 ----------------
__global__ __launch_bounds__(256) void cvt_x_kernel(const float* __restrict__ x,
                                                    unsigned short* __restrict__ xbf) {
    int i = blockIdx.x * 256 + threadIdx.x;            // 8 elems per thread
    float4 a = ((const float4*)x)[i * 2];
    float4 b = ((const float4*)x)[i * 2 + 1];
    ushort4 lo = { f2bf(a.x), f2bf(a.y), f2bf(a.z), f2bf(a.w) };
    ushort4 hi = { f2bf(b.x), f2bf(b.y), f2bf(b.z), f2bf(b.w) };
    ((ushort4*)xbf)[i * 2]     = lo;
    ((ushort4*)xbf)[i * 2 + 1] = hi;
}

// ---------------- prepass: W [E][R][C] fp32 -> WT [E][C][R] bf16 ----------------
__global__ __launch_bounds__(256) void transpose_cvt_kernel(const float* __restrict__ in,
                                                            unsigned short* __restrict__ out,
                                                            int R, int C) {
    __shared__ unsigned short t[64][66];               // pad 2 shorts: conflict-free
    int e  = blockIdx.z;
    int r0 = blockIdx.y * 64, c0 = blockIdx.x * 64;
    int tid = threadIdx.x;
    int ci = tid & 63, ri = tid >> 6;
    const float* src = in + ((size_t)e * R + r0) * C + c0;
#pragma unroll
    for (int j = 0; j < 16; ++j) {
        int r = ri + j * 4;
        t[ci][r] = f2bf(src[(size_t)r * C + ci]);      // coalesced read along C
    }
    __syncthreads();
    int r2 = (tid & 15) * 4, c2 = tid >> 4;            // c2 in 0..15
    unsigned short* dst = out + ((size_t)e * C + c0) * R + r0;
#pragma unroll
    for (int j = 0; j < 4; ++j) {
        int c = c2 + j * 16;
        ushort4 v = { t[c][r2], t[c][r2 + 1], t[c][r2 + 2], t[c][r2 + 3] };
        *(ushort4*)&dst[(size_t)c * R + r2] = v;       // coalesced write along R
    }
}

// ---------------- gating: logits, unimix softmax, top-2, renorm ----------------
__global__ void gating_kernel(const float* __restrict__ x, const float* __restrict__ Wg,
                              const float* __restrict__ bg, int* __restrict__ counts,
                              int* __restrict__ tok_list, float* __restrict__ wt_list,
                              float* __restrict__ ssq) {
    int lane = threadIdx.x & 63;
    int wid  = threadIdx.x >> 6;
    int t = blockIdx.x * 4 + wid;           // one wave per token
    const float* xr = x + (size_t)t * DD;
    float acc[EE];
#pragma unroll
    for (int e = 0; e < EE; ++e) acc[e] = 0.f;
    for (int d = lane; d < DD; d += 64) {
        float xv = xr[d];
        const float* wr = Wg + d * EE;
#pragma unroll
        for (int e = 0; e < EE; ++e) acc[e] += xv * wr[e];
    }
#pragma unroll
    for (int off = 32; off; off >>= 1)
#pragma unroll
        for (int e = 0; e < EE; ++e) acc[e] += __shfl_xor(acc[e], off, 64);

    if (lane == 0) {
        float p[EE]; float m = -1e30f;
#pragma unroll
        for (int e = 0; e < EE; ++e) { p[e] = acc[e] + bg[e]; m = fmaxf(m, p[e]); }
        float s = 0.f;
#pragma unroll
        for (int e = 0; e < EE; ++e) { p[e] = expf(p[e] - m); s += p[e]; }
        float inv = 1.f / s, q = 0.f;
#pragma unroll
        for (int e = 0; e < EE; ++e) { p[e] = 0.99f * p[e] * inv + 0.00125f; q += p[e] * p[e]; }
        ssq[t] = q;
        int i1 = 0;
#pragma unroll
        for (int e = 1; e < EE; ++e) if (p[e] > p[i1]) i1 = e;    // lowest idx on tie
        int i2 = (i1 == 0) ? 1 : 0;
#pragma unroll
        for (int e = 0; e < EE; ++e) if (e != i1 && p[e] > p[i2]) i2 = e;
        float sw = p[i1] + p[i2];
        float w1 = p[i1] / sw, w2 = p[i2] / sw;
        int pos1 = atomicAdd(&counts[i1], 1);
        tok_list[i1 * BT + pos1] = t; wt_list[i1 * BT + pos1] = w1;
        int pos2 = atomicAdd(&counts[i2], 1);
        tok_list[i2 * BT + pos2] = t; wt_list[i2 * BT + pos2] = w2;
    }
}

__global__ void offsets_kernel(const int* __restrict__ counts, int* __restrict__ offs) {
    if (threadIdx.x == 0) {
        int a = 0;
        for (int e = 0; e < EE; ++e) { offs[e] = a; a += counts[e]; }
        offs[EE] = a;
    }
}

// ---------------- GEMM1: h = gelu(x_gathered @ W1 + b1) -> bf16 hbuf ----------------
// A: xbf rows gathered by token list; B: W1T [e][h][d] bf16 (k = d contiguous).
// LDS [128][32] bf16 linear, staged via global_load_lds w=16 with granule XOR-swizzle.
__global__ __launch_bounds__(256) void gemm1_kernel(
        const unsigned short* __restrict__ xbf, const unsigned short* __restrict__ W1T,
        const float* __restrict__ b1, const int* __restrict__ counts,
        const int* __restrict__ offs, const int* __restrict__ tok_list,
        unsigned short* __restrict__ hbuf) {
    int e   = blockIdx.z;
    int cnt = counts[e];
    int m0  = blockIdx.y * 128;
    if (m0 >= cnt) return;
    int h0   = blockIdx.x * 128;
    int base = offs[e];

    __shared__ __align__(16) unsigned short As[128 * 32];
    __shared__ __align__(16) unsigned short Bs[128 * 32];

    int tid = threadIdx.x, l = tid & 63, w = tid >> 6;
    int wr = w >> 1, wc = w & 1;

    // staging rows: wave w covers rows w*32 .. w*32+31 in two 1KB calls
    int rs0 = w * 32 + (l >> 2);
    int rs1 = rs0 + 16;
    int g0  = (l & 3) ^ ((rs0 >> 1) & 3);      // swizzled source granule
    int g1  = (l & 3) ^ ((rs1 >> 1) & 3);
    int ra0 = m0 + rs0; if (ra0 >= cnt) ra0 = cnt - 1;
    int ra1 = m0 + rs1; if (ra1 >= cnt) ra1 = cnt - 1;
    const unsigned short* pa0 = xbf + (size_t)tok_list[e * BT + ra0] * DD + g0 * 8;
    const unsigned short* pa1 = xbf + (size_t)tok_list[e * BT + ra1] * DD + g1 * 8;
    const unsigned short* pb0 = W1T + ((size_t)e * HH + h0 + rs0) * DD + g0 * 8;
    const unsigned short* pb1 = W1T + ((size_t)e * HH + h0 + rs1) * DD + g1 * 8;
    unsigned short* lA = As + w * 1024;        // wave-uniform LDS bases (shorts)
    unsigned short* lB = Bs + w * 1024;

    int slot = (l >> 4) ^ ((l >> 1) & 3);      // swizzled read granule (lane-only)
    int arow = wr * 64 + (l & 15);
    int brow = wc * 64 + (l & 15);

    f32x4 acc[4][4];
#pragma unroll
    for (int i = 0; i < 4; ++i)
#pragma unroll
        for (int j = 0; j < 4; ++j) acc[i][j] = (f32x4){0.f, 0.f, 0.f, 0.f};

    for (int ks = 0; ks < DD / 32; ++ks) {
        __syncthreads();                       // previous compute done
        gload16(pa0, lA);
        gload16(pa1, lA + 512);
        gload16(pb0, lB);
        gload16(pb1, lB + 512);
        pa0 += 32; pa1 += 32; pb0 += 32; pb1 += 32;
        __syncthreads();                       // compiler drains vmcnt here

        bf16x8 af[4], bfr[4];
#pragma unroll
        for (int f = 0; f < 4; ++f) {
            af[f]  = *(const bf16x8*)&As[(arow + f * 16) * 32 + slot * 8];
            bfr[f] = *(const bf16x8*)&Bs[(brow + f * 16) * 32 + slot * 8];
        }
#pragma unroll
        for (int fm = 0; fm < 4; ++fm)
#pragma unroll
            for (int fn = 0; fn < 4; ++fn)
                acc[fm][fn] = __builtin_amdgcn_mfma_f32_16x16x32_bf16(af[fm], bfr[fn], acc[fm][fn], 0, 0, 0);
    }

    const float* b1e = b1 + e * HH;
#pragma unroll
    for (int fm = 0; fm < 4; ++fm) {
#pragma unroll
        for (int j = 0; j < 4; ++j) {
            int r = m0 + wr * 64 + fm * 16 + (l >> 4) * 4 + j;
            if (r >= cnt) continue;
            size_t rb = (size_t)(base + r) * HH;
#pragma unroll
            for (int fn = 0; fn < 4; ++fn) {
                int h = h0 + wc * 64 + fn * 16 + (l & 15);
                float v = acc[fm][fn][j] + b1e[h];
                v = 0.5f * v * (1.f + erff(v * 0.70710678118654752f));   // exact gelu
                hbuf[rb + h] = f2bf(v);
            }
        }
    }
}

// ---------------- GEMM2: out += w * (h @ W2 + b2) ----------------
__global__ __launch_bounds__(256) void gemm2_kernel(
        const unsigned short* __restrict__ hbuf, const unsigned short* __restrict__ W2T,
        const float* __restrict__ b2, const int* __restrict__ counts, const int* __restrict__ offs,
        const int* __restrict__ tok_list, const float* __restrict__ wt_list,
        float* __restrict__ out) {
    int e   = blockIdx.z;
    int cnt = counts[e];
    int m0  = blockIdx.y * 128;
    if (m0 >= cnt) return;
    int d0   = blockIdx.x * 128;
    int base = offs[e];

    __shared__ __align__(16) unsigned short As[128 * 32];
    __shared__ __align__(16) unsigned short Bs[128 * 32];

    int tid = threadIdx.x, l = tid & 63, w = tid >> 6;
    int wr = w >> 1, wc = w & 1;

    int rs0 = w * 32 + (l >> 2);
    int rs1 = rs0 + 16;
    int g0  = (l & 3) ^ ((rs0 >> 1) & 3);
    int g1  = (l & 3) ^ ((rs1 >> 1) & 3);
    int ra0 = m0 + rs0; if (ra0 >= cnt) ra0 = cnt - 1;
    int ra1 = m0 + rs1; if (ra1 >= cnt) ra1 = cnt - 1;
    const unsigned short* pa0 = hbuf + (size_t)(base + ra0) * HH + g0 * 8;
    const unsigned short* pa1 = hbuf + (size_t)(base + ra1) * HH + g1 * 8;
    const unsigned short* pb0 = W2T + ((size_t)e * DD + d0 + rs0) * HH + g0 * 8;
    const unsigned short* pb1 = W2T + ((size_t)e * DD + d0 + rs1) * HH + g1 * 8;
    unsigned short* lA = As + w * 1024;
    unsigned short* lB = Bs + w * 1024;

    int slot = (l >> 4) ^ ((l >> 1) & 3);
    int arow = wr * 64 + (l & 15);
    int brow = wc * 64 + (l & 15);

    f32x4 acc[4][4];
#pragma unroll
    for (int i = 0; i < 4; ++i)
#pragma unroll
        for (int j = 0; j < 4; ++j) acc[i][j] = (f32x4){0.f, 0.f, 0.f, 0.f};

    for (int ks = 0; ks < HH / 32; ++ks) {
        __syncthreads();
        gload16(pa0, lA);
        gload16(pa1, lA + 512);
        gload16(pb0, lB);
        gload16(pb1, lB + 512);
        pa0 += 32; pa1 += 32; pb0 += 32; pb1 += 32;
        __syncthreads();

        bf16x8 af[4], bfr[4];
#pragma unroll
        for (int f = 0; f < 4; ++f) {
            af[f]  = *(const bf16x8*)&As[(arow + f * 16) * 32 + slot * 8];
            bfr[f] = *(const bf16x8*)&Bs[(brow + f * 16) * 32 + slot * 8];
        }
#pragma unroll
        for (int fm = 0; fm < 4; ++fm)
#pragma unroll
            for (int fn = 0; fn < 4; ++fn)
                acc[fm][fn] = __builtin_amdgcn_mfma_f32_16x16x32_bf16(af[fm], bfr[fn], acc[fm][fn], 0, 0, 0);
    }

    const float* b2e = b2 + e * DD;
#pragma unroll
    for (int fm = 0; fm < 4; ++fm) {
#pragma unroll
        for (int j = 0; j < 4; ++j) {
            int r = m0 + wr * 64 + fm * 16 + (l >> 4) * 4 + j;
            if (r >= cnt) continue;
            int token = tok_list[e * BT + r];
            float wgt = wt_list[e * BT + r];
            float* orow = out + (size_t)token * DD;
#pragma unroll
            for (int fn = 0; fn < 4; ++fn) {
                int d = d0 + wc * 64 + fn * 16 + (l & 15);
                float v = acc[fm][fn][j] + b2e[d];
                atomicAdd(&orow[d], wgt * v);   // exactly 2 adds/elem, commutative -> deterministic
            }
        }
    }
}

// ---------------- aux = mean(sum probs^2) * E ----------------
__global__ void aux_kernel(const float* __restrict__ ssq, float* __restrict__ out_aux) {
    __shared__ float red[4];
    float s = 0.f;
    for (int i = threadIdx.x; i < BT; i += 256) s += ssq[i];
#pragma unroll
    for (int off = 32; off; off >>= 1) s += __shfl_xor(s, off, 64);
    if ((threadIdx.x & 63) == 0) red[threadIdx.x >> 6] = s;
    __syncthreads();
    if (threadIdx.x == 0)
        out_aux[0] = (red[0] + red[1] + red[2] + red[3]) * (float)EE / (float)BT;
}

extern "C" void kernel_launch(void* const* d_in, const int* in_sizes, int n_in,
                              void* d_out, int out_size, void* d_ws, size_t ws_size,
                              hipStream_t stream) {
    const float* x  = (const float*)d_in[0];
    const float* Wg = (const float*)d_in[1];
    const float* bg = (const float*)d_in[2];
    const float* W1 = (const float*)d_in[3];
    const float* b1 = (const float*)d_in[4];
    const float* W2 = (const float*)d_in[5];
    const float* b2 = (const float*)d_in[6];
    float* out = (float*)d_out;

    char* wsb = (char*)d_ws;
    int*   counts = (int*)wsb;                          // 8 ints
    int*   offs   = (int*)(wsb + 64);                   // 9 ints
    int*   tok    = (int*)(wsb + 256);                  // 8*8192 ints   -> ends 262400
    float* wts    = (float*)(wsb + 262400);             // 8*8192 floats -> ends 524544
    float* ssq    = (float*)(wsb + 524544);             // 8192 floats   -> ends 557312
    unsigned short* xbf  = (unsigned short*)(wsb + 557312);      // 16 MB -> ends 17334528
    unsigned short* W1T  = (unsigned short*)(wsb + 17334528);    // 32 MB -> ends 50888960
    unsigned short* W2T  = (unsigned short*)(wsb + 50888960);    // 32 MB -> ends 84443392
    unsigned short* hbuf = (unsigned short*)(wsb + 84443392);    // 64 MB -> ends 151552256

    hipMemsetAsync(wsb, 0, 64, stream);                                  // counts
    hipMemsetAsync(out, 0, (size_t)BT * DD * sizeof(float), stream);     // out accumulator

    cvt_x_kernel<<<BT * DD / (256 * 8), 256, 0, stream>>>(x, xbf);
    transpose_cvt_kernel<<<dim3(HH / 64, DD / 64, EE), 256, 0, stream>>>(W1, W1T, DD, HH);
    transpose_cvt_kernel<<<dim3(DD / 64, HH / 64, EE), 256, 0, stream>>>(W2, W2T, HH, DD);
    gating_kernel<<<BT / 4, 256, 0, stream>>>(x, Wg, bg, counts, tok, wts, ssq);
    offsets_kernel<<<1, 64, 0, stream>>>(counts, offs);
    gemm1_kernel<<<dim3(HH / 128, BT / 128, EE), 256, 0, stream>>>(xbf, W1T, b1, counts, offs, tok, hbuf);
    gemm2_kernel<<<dim3(DD / 128, BT / 128, EE), 256, 0, stream>>>(hbuf, W2T, b2, counts, offs, tok, wts, out);
    aux_kernel<<<1, 256, 0, stream>>>(ssq, out + (size_t)BT * DD);
}

// Round 3
// 400.570 us; speedup vs baseline: 1.7605x; 1.4485x over previous
//
#include <hip/hip_runtime.h>
#include <hip/hip_bf16.h>
#include <cmath>

#define BT 8192      // B*T tokens
#define DD 1024      // model dim
#define EE 8         // experts
#define HH 2048      // hidden

typedef __attribute__((ext_vector_type(8))) short bf16x8;
typedef __attribute__((ext_vector_type(4))) float f32x4;

__device__ __forceinline__ unsigned short f2bf(float f) {
    union { float f; unsigned u; } v; v.f = f;
    unsigned r = v.u + 0x7FFFu + ((v.u >> 16) & 1u);   // RNE
    return (unsigned short)(r >> 16);
}

// async global->LDS, 16B per lane; LDS dest = wave-uniform base + lane*16
__device__ __forceinline__ void gload16(const void* g, void* l) {
    __builtin_amdgcn_global_load_lds(
        (const __attribute__((address_space(1))) void*)g,
        (__attribute__((address_space(3))) void*)l, 16, 0, 0);
}

// ---------------- prepass: x fp32 -> bf16 ----------------
__global__ __launch_bounds__(256) void cvt_x_kernel(const float* __restrict__ x,
                                                    unsigned short* __restrict__ xbf) {
    int i = blockIdx.x * 256 + threadIdx.x;            // 8 elems per thread
    float4 a = ((const float4*)x)[i * 2];
    float4 b = ((const float4*)x)[i * 2 + 1];
    ushort4 lo = { f2bf(a.x), f2bf(a.y), f2bf(a.z), f2bf(a.w) };
    ushort4 hi = { f2bf(b.x), f2bf(b.y), f2bf(b.z), f2bf(b.w) };
    ((ushort4*)xbf)[i * 2]     = lo;
    ((ushort4*)xbf)[i * 2 + 1] = hi;
}

// ---------------- prepass: W [E][R][C] fp32 -> WT [E][C][R] bf16 ----------------
__global__ __launch_bounds__(256) void transpose_cvt_kernel(const float* __restrict__ in,
                                                            unsigned short* __restrict__ out,
                                                            int R, int C) {
    __shared__ unsigned short t[64][66];               // pad 2 shorts: conflict-free
    int e  = blockIdx.z;
    int r0 = blockIdx.y * 64, c0 = blockIdx.x * 64;
    int tid = threadIdx.x;
    int ci = tid & 63, ri = tid >> 6;
    const float* src = in + ((size_t)e * R + r0) * C + c0;
#pragma unroll
    for (int j = 0; j < 16; ++j) {
        int r = ri + j * 4;
        t[ci][r] = f2bf(src[(size_t)r * C + ci]);      // coalesced read along C
    }
    __syncthreads();
    int r2 = (tid & 15) * 4, c2 = tid >> 4;            // c2 in 0..15
    unsigned short* dst = out + ((size_t)e * C + c0) * R + r0;
#pragma unroll
    for (int j = 0; j < 4; ++j) {
        int c = c2 + j * 16;
        ushort4 v = { t[c][r2], t[c][r2 + 1], t[c][r2 + 2], t[c][r2 + 3] };
        *(ushort4*)&dst[(size_t)c * R + r2] = v;       // coalesced write along R
    }
}

// ---------------- gating: logits, unimix softmax, top-2 — NO atomics ----------------
__global__ void gating_kernel(const float* __restrict__ x, const float* __restrict__ Wg,
                              const float* __restrict__ bg, int* __restrict__ tk_pack,
                              float* __restrict__ tk_w, float* __restrict__ ssq) {
    int lane = threadIdx.x & 63;
    int wid  = threadIdx.x >> 6;
    int t = blockIdx.x * 4 + wid;           // one wave per token
    const float* xr = x + (size_t)t * DD;
    float acc[EE];
#pragma unroll
    for (int e = 0; e < EE; ++e) acc[e] = 0.f;
    for (int d = lane; d < DD; d += 64) {
        float xv = xr[d];
        const float* wr = Wg + d * EE;
#pragma unroll
        for (int e = 0; e < EE; ++e) acc[e] += xv * wr[e];
    }
#pragma unroll
    for (int off = 32; off; off >>= 1)
#pragma unroll
        for (int e = 0; e < EE; ++e) acc[e] += __shfl_xor(acc[e], off, 64);

    if (lane == 0) {
        float p[EE]; float m = -1e30f;
#pragma unroll
        for (int e = 0; e < EE; ++e) { p[e] = acc[e] + bg[e]; m = fmaxf(m, p[e]); }
        float s = 0.f;
#pragma unroll
        for (int e = 0; e < EE; ++e) { p[e] = expf(p[e] - m); s += p[e]; }
        float inv = 1.f / s, q = 0.f;
#pragma unroll
        for (int e = 0; e < EE; ++e) { p[e] = 0.99f * p[e] * inv + 0.00125f; q += p[e] * p[e]; }
        ssq[t] = q;
        int i1 = 0;
#pragma unroll
        for (int e = 1; e < EE; ++e) if (p[e] > p[i1]) i1 = e;    // lowest idx on tie
        int i2 = (i1 == 0) ? 1 : 0;
#pragma unroll
        for (int e = 0; e < EE; ++e) if (e != i1 && p[e] > p[i2]) i2 = e;
        tk_pack[t] = i1 | (i2 << 4);
        tk_w[t] = p[i1] / (p[i1] + p[i2]);             // w2 = 1 - w1
    }
}

// ---------------- scatter: per-block LDS histogram + 8 global atomics/block ----------------
__global__ __launch_bounds__(256) void scatter_kernel(const int* __restrict__ tk_pack,
                                                      const float* __restrict__ tk_w,
                                                      int* __restrict__ counts,
                                                      int* __restrict__ tok_list,
                                                      float* __restrict__ wt_list) {
    __shared__ int lcnt[EE];
    __shared__ int gbase[EE];
    int tid = threadIdx.x;
    int t = blockIdx.x * 256 + tid;
    if (tid < EE) lcnt[tid] = 0;
    __syncthreads();
    int pk = tk_pack[t];
    int i1 = pk & 15, i2 = pk >> 4;
    float w1 = tk_w[t];
    int p1 = atomicAdd(&lcnt[i1], 1);                  // LDS atomics: cheap
    int p2 = atomicAdd(&lcnt[i2], 1);
    __syncthreads();
    if (tid < EE) gbase[tid] = atomicAdd(&counts[tid], lcnt[tid]);   // 8 global atomics/block
    __syncthreads();
    int q1 = gbase[i1] + p1, q2 = gbase[i2] + p2;
    tok_list[i1 * BT + q1] = t;  wt_list[i1 * BT + q1] = w1;
    tok_list[i2 * BT + q2] = t;  wt_list[i2 * BT + q2] = 1.f - w1;
}

__global__ void offsets_kernel(const int* __restrict__ counts, int* __restrict__ offs) {
    if (threadIdx.x == 0) {
        int a = 0;
        for (int e = 0; e < EE; ++e) { offs[e] = a; a += counts[e]; }
        offs[EE] = a;
    }
}

// ---------------- GEMM1: h = gelu(x_gathered @ W1 + b1) -> bf16 hbuf ----------------
__global__ __launch_bounds__(256) void gemm1_kernel(
        const unsigned short* __restrict__ xbf, const unsigned short* __restrict__ W1T,
        const float* __restrict__ b1, const int* __restrict__ counts,
        const int* __restrict__ offs, const int* __restrict__ tok_list,
        unsigned short* __restrict__ hbuf) {
    int e   = blockIdx.z;
    int cnt = counts[e];
    int m0  = blockIdx.y * 128;
    if (m0 >= cnt) return;
    int h0   = blockIdx.x * 128;
    int base = offs[e];

    __shared__ __align__(16) unsigned short As[128 * 32];
    __shared__ __align__(16) unsigned short Bs[128 * 32];

    int tid = threadIdx.x, l = tid & 63, w = tid >> 6;
    int wr = w >> 1, wc = w & 1;

    int rs0 = w * 32 + (l >> 2);
    int rs1 = rs0 + 16;
    int g0  = (l & 3) ^ ((rs0 >> 1) & 3);      // swizzled source granule
    int g1  = (l & 3) ^ ((rs1 >> 1) & 3);
    int ra0 = m0 + rs0; if (ra0 >= cnt) ra0 = cnt - 1;
    int ra1 = m0 + rs1; if (ra1 >= cnt) ra1 = cnt - 1;
    const unsigned short* pa0 = xbf + (size_t)tok_list[e * BT + ra0] * DD + g0 * 8;
    const unsigned short* pa1 = xbf + (size_t)tok_list[e * BT + ra1] * DD + g1 * 8;
    const unsigned short* pb0 = W1T + ((size_t)e * HH + h0 + rs0) * DD + g0 * 8;
    const unsigned short* pb1 = W1T + ((size_t)e * HH + h0 + rs1) * DD + g1 * 8;
    unsigned short* lA = As + w * 1024;
    unsigned short* lB = Bs + w * 1024;

    int slot = (l >> 4) ^ ((l >> 1) & 3);      // swizzled read granule
    int arow = wr * 64 + (l & 15);
    int brow = wc * 64 + (l & 15);

    f32x4 acc[4][4];
#pragma unroll
    for (int i = 0; i < 4; ++i)
#pragma unroll
        for (int j = 0; j < 4; ++j) acc[i][j] = (f32x4){0.f, 0.f, 0.f, 0.f};

    for (int ks = 0; ks < DD / 32; ++ks) {
        __syncthreads();
        gload16(pa0, lA);
        gload16(pa1, lA + 512);
        gload16(pb0, lB);
        gload16(pb1, lB + 512);
        pa0 += 32; pa1 += 32; pb0 += 32; pb1 += 32;
        __syncthreads();

        bf16x8 af[4], bfr[4];
#pragma unroll
        for (int f = 0; f < 4; ++f) {
            af[f]  = *(const bf16x8*)&As[(arow + f * 16) * 32 + slot * 8];
            bfr[f] = *(const bf16x8*)&Bs[(brow + f * 16) * 32 + slot * 8];
        }
#pragma unroll
        for (int fm = 0; fm < 4; ++fm)
#pragma unroll
            for (int fn = 0; fn < 4; ++fn)
                acc[fm][fn] = __builtin_amdgcn_mfma_f32_16x16x32_bf16(af[fm], bfr[fn], acc[fm][fn], 0, 0, 0);
    }

    const float* b1e = b1 + e * HH;
#pragma unroll
    for (int fm = 0; fm < 4; ++fm) {
#pragma unroll
        for (int j = 0; j < 4; ++j) {
            int r = m0 + wr * 64 + fm * 16 + (l >> 4) * 4 + j;
            if (r >= cnt) continue;
            size_t rb = (size_t)(base + r) * HH;
#pragma unroll
            for (int fn = 0; fn < 4; ++fn) {
                int h = h0 + wc * 64 + fn * 16 + (l & 15);
                float v = acc[fm][fn][j] + b1e[h];
                v = 0.5f * v * (1.f + erff(v * 0.70710678118654752f));   // exact gelu
                hbuf[rb + h] = f2bf(v);
            }
        }
    }
}

// ---------------- GEMM2: out += w * (h @ W2 + b2) ----------------
__global__ __launch_bounds__(256) void gemm2_kernel(
        const unsigned short* __restrict__ hbuf, const unsigned short* __restrict__ W2T,
        const float* __restrict__ b2, const int* __restrict__ counts, const int* __restrict__ offs,
        const int* __restrict__ tok_list, const float* __restrict__ wt_list,
        float* __restrict__ out) {
    int e   = blockIdx.z;
    int cnt = counts[e];
    int m0  = blockIdx.y * 128;
    if (m0 >= cnt) return;
    int d0   = blockIdx.x * 128;
    int base = offs[e];

    __shared__ __align__(16) unsigned short As[128 * 32];
    __shared__ __align__(16) unsigned short Bs[128 * 32];

    int tid = threadIdx.x, l = tid & 63, w = tid >> 6;
    int wr = w >> 1, wc = w & 1;

    int rs0 = w * 32 + (l >> 2);
    int rs1 = rs0 + 16;
    int g0  = (l & 3) ^ ((rs0 >> 1) & 3);
    int g1  = (l & 3) ^ ((rs1 >> 1) & 3);
    int ra0 = m0 + rs0; if (ra0 >= cnt) ra0 = cnt - 1;
    int ra1 = m0 + rs1; if (ra1 >= cnt) ra1 = cnt - 1;
    const unsigned short* pa0 = hbuf + (size_t)(base + ra0) * HH + g0 * 8;
    const unsigned short* pa1 = hbuf + (size_t)(base + ra1) * HH + g1 * 8;
    const unsigned short* pb0 = W2T + ((size_t)e * DD + d0 + rs0) * HH + g0 * 8;
    const unsigned short* pb1 = W2T + ((size_t)e * DD + d0 + rs1) * HH + g1 * 8;
    unsigned short* lA = As + w * 1024;
    unsigned short* lB = Bs + w * 1024;

    int slot = (l >> 4) ^ ((l >> 1) & 3);
    int arow = wr * 64 + (l & 15);
    int brow = wc * 64 + (l & 15);

    f32x4 acc[4][4];
#pragma unroll
    for (int i = 0; i < 4; ++i)
#pragma unroll
        for (int j = 0; j < 4; ++j) acc[i][j] = (f32x4){0.f, 0.f, 0.f, 0.f};

    for (int ks = 0; ks < HH / 32; ++ks) {
        __syncthreads();
        gload16(pa0, lA);
        gload16(pa1, lA + 512);
        gload16(pb0, lB);
        gload16(pb1, lB + 512);
        pa0 += 32; pa1 += 32; pb0 += 32; pb1 += 32;
        __syncthreads();

        bf16x8 af[4], bfr[4];
#pragma unroll
        for (int f = 0; f < 4; ++f) {
            af[f]  = *(const bf16x8*)&As[(arow + f * 16) * 32 + slot * 8];
            bfr[f] = *(const bf16x8*)&Bs[(brow + f * 16) * 32 + slot * 8];
        }
#pragma unroll
        for (int fm = 0; fm < 4; ++fm)
#pragma unroll
            for (int fn = 0; fn < 4; ++fn)
                acc[fm][fn] = __builtin_amdgcn_mfma_f32_16x16x32_bf16(af[fm], bfr[fn], acc[fm][fn], 0, 0, 0);
    }

    const float* b2e = b2 + e * DD;
#pragma unroll
    for (int fm = 0; fm < 4; ++fm) {
#pragma unroll
        for (int j = 0; j < 4; ++j) {
            int r = m0 + wr * 64 + fm * 16 + (l >> 4) * 4 + j;
            if (r >= cnt) continue;
            int token = tok_list[e * BT + r];
            float wgt = wt_list[e * BT + r];
            float* orow = out + (size_t)token * DD;
#pragma unroll
            for (int fn = 0; fn < 4; ++fn) {
                int d = d0 + wc * 64 + fn * 16 + (l & 15);
                float v = acc[fm][fn][j] + b2e[d];
                atomicAdd(&orow[d], wgt * v);   // exactly 2 adds/elem, commutative -> deterministic
            }
        }
    }
}

// ---------------- aux = mean(sum probs^2) * E ----------------
__global__ void aux_kernel(const float* __restrict__ ssq, float* __restrict__ out_aux) {
    __shared__ float red[4];
    float s = 0.f;
    for (int i = threadIdx.x; i < BT; i += 256) s += ssq[i];
#pragma unroll
    for (int off = 32; off; off >>= 1) s += __shfl_xor(s, off, 64);
    if ((threadIdx.x & 63) == 0) red[threadIdx.x >> 6] = s;
    __syncthreads();
    if (threadIdx.x == 0)
        out_aux[0] = (red[0] + red[1] + red[2] + red[3]) * (float)EE / (float)BT;
}

extern "C" void kernel_launch(void* const* d_in, const int* in_sizes, int n_in,
                              void* d_out, int out_size, void* d_ws, size_t ws_size,
                              hipStream_t stream) {
    const float* x  = (const float*)d_in[0];
    const float* Wg = (const float*)d_in[1];
    const float* bg = (const float*)d_in[2];
    const float* W1 = (const float*)d_in[3];
    const float* b1 = (const float*)d_in[4];
    const float* W2 = (const float*)d_in[5];
    const float* b2 = (const float*)d_in[6];
    float* out = (float*)d_out;

    char* wsb = (char*)d_ws;
    int*   counts = (int*)wsb;                          // 8 ints
    int*   offs   = (int*)(wsb + 64);                   // 9 ints
    int*   tok    = (int*)(wsb + 256);                  // 8*8192 ints   -> ends 262400
    float* wts    = (float*)(wsb + 262400);             // 8*8192 floats -> ends 524544
    float* ssq    = (float*)(wsb + 524544);             // 8192 floats   -> ends 557312
    unsigned short* xbf  = (unsigned short*)(wsb + 557312);      // 16 MB -> ends 17334528
    unsigned short* W1T  = (unsigned short*)(wsb + 17334528);    // 32 MB -> ends 50888960
    unsigned short* W2T  = (unsigned short*)(wsb + 50888960);    // 32 MB -> ends 84443392
    unsigned short* hbuf = (unsigned short*)(wsb + 84443392);    // 64 MB -> ends 151552256
    // tk_pack/tk_w overlay the hbuf region (dead until gemm1 runs, after scatter)
    int*   tk_pack = (int*)(wsb + 84443392);            // 32 KB
    float* tk_w    = (float*)(wsb + 84443392 + 32768);  // 32 KB

    hipMemsetAsync(wsb, 0, 64, stream);                                  // counts
    hipMemsetAsync(out, 0, (size_t)BT * DD * sizeof(float), stream);     // out accumulator

    cvt_x_kernel<<<BT * DD / (256 * 8), 256, 0, stream>>>(x, xbf);
    transpose_cvt_kernel<<<dim3(HH / 64, DD / 64, EE), 256, 0, stream>>>(W1, W1T, DD, HH);
    transpose_cvt_kernel<<<dim3(DD / 64, HH / 64, EE), 256, 0, stream>>>(W2, W2T, HH, DD);
    gating_kernel<<<BT / 4, 256, 0, stream>>>(x, Wg, bg, tk_pack, tk_w, ssq);
    scatter_kernel<<<BT / 256, 256, 0, stream>>>(tk_pack, tk_w, counts, tok, wts);
    offsets_kernel<<<1, 64, 0, stream>>>(counts, offs);
    gemm1_kernel<<<dim3(HH / 128, BT / 128, EE), 256, 0, stream>>>(xbf, W1T, b1, counts, offs, tok, hbuf);
    gemm2_kernel<<<dim3(DD / 128, BT / 128, EE), 256, 0, stream>>>(hbuf, W2T, b2, counts, offs, tok, wts, out);
    aux_kernel<<<1, 256, 0, stream>>>(ssq, out + (size_t)BT * DD);
}

// Round 4
// 313.484 us; speedup vs baseline: 2.2496x; 1.2778x over previous
//
#include <hip/hip_runtime.h>
#include <hip/hip_bf16.h>
#include <cmath>

#define BT 8192      // B*T tokens
#define DD 1024      // model dim
#define EE 8         // experts
#define HH 2048      // hidden

typedef __attribute__((ext_vector_type(8))) short bf16x8;
typedef __attribute__((ext_vector_type(4))) float f32x4;

__device__ __forceinline__ unsigned short f2bf(float f) {
    union { float f; unsigned u; } v; v.f = f;
    unsigned r = v.u + 0x7FFFu + ((v.u >> 16) & 1u);   // RNE
    return (unsigned short)(r >> 16);
}

__device__ __forceinline__ float bf2f(unsigned short s) {
    union { unsigned u; float f; } v; v.u = ((unsigned)s) << 16;
    return v.f;
}

// async global->LDS, 16B per lane; LDS dest = wave-uniform base + lane*16
__device__ __forceinline__ void gload16(const void* g, void* l) {
    __builtin_amdgcn_global_load_lds(
        (const __attribute__((address_space(1))) void*)g,
        (__attribute__((address_space(3))) void*)l, 16, 0, 0);
}

// ---------------- prepass: x fp32 -> bf16 ----------------
__global__ __launch_bounds__(256) void cvt_x_kernel(const float* __restrict__ x,
                                                    unsigned short* __restrict__ xbf) {
    int i = blockIdx.x * 256 + threadIdx.x;            // 8 elems per thread
    float4 a = ((const float4*)x)[i * 2];
    float4 b = ((const float4*)x)[i * 2 + 1];
    ushort4 lo = { f2bf(a.x), f2bf(a.y), f2bf(a.z), f2bf(a.w) };
    ushort4 hi = { f2bf(b.x), f2bf(b.y), f2bf(b.z), f2bf(b.w) };
    ((ushort4*)xbf)[i * 2]     = lo;
    ((ushort4*)xbf)[i * 2 + 1] = hi;
}

// ---------------- prepass: W [E][R][C] fp32 -> WT [E][C][R] bf16 ----------------
__global__ __launch_bounds__(256) void transpose_cvt_kernel(const float* __restrict__ in,
                                                            unsigned short* __restrict__ out,
                                                            int R, int C) {
    __shared__ unsigned short t[64][66];               // pad 2 shorts: conflict-free
    int e  = blockIdx.z;
    int r0 = blockIdx.y * 64, c0 = blockIdx.x * 64;
    int tid = threadIdx.x;
    int ci = tid & 63, ri = tid >> 6;
    const float* src = in + ((size_t)e * R + r0) * C + c0;
#pragma unroll
    for (int j = 0; j < 16; ++j) {
        int r = ri + j * 4;
        t[ci][r] = f2bf(src[(size_t)r * C + ci]);      // coalesced read along C
    }
    __syncthreads();
    int r2 = (tid & 15) * 4, c2 = tid >> 4;            // c2 in 0..15
    unsigned short* dst = out + ((size_t)e * C + c0) * R + r0;
#pragma unroll
    for (int j = 0; j < 4; ++j) {
        int c = c2 + j * 16;
        ushort4 v = { t[c][r2], t[c][r2 + 1], t[c][r2 + 2], t[c][r2 + 3] };
        *(ushort4*)&dst[(size_t)c * R + r2] = v;       // coalesced write along R
    }
}

// ---------------- gating: logits, unimix softmax, top-2 — NO atomics ----------------
__global__ void gating_kernel(const float* __restrict__ x, const float* __restrict__ Wg,
                              const float* __restrict__ bg, int* __restrict__ tk_pack,
                              float* __restrict__ tk_w, float* __restrict__ ssq) {
    int lane = threadIdx.x & 63;
    int wid  = threadIdx.x >> 6;
    int t = blockIdx.x * 4 + wid;           // one wave per token
    const float* xr = x + (size_t)t * DD;
    float acc[EE];
#pragma unroll
    for (int e = 0; e < EE; ++e) acc[e] = 0.f;
    for (int d = lane; d < DD; d += 64) {
        float xv = xr[d];
        const float* wr = Wg + d * EE;
#pragma unroll
        for (int e = 0; e < EE; ++e) acc[e] += xv * wr[e];
    }
#pragma unroll
    for (int off = 32; off; off >>= 1)
#pragma unroll
        for (int e = 0; e < EE; ++e) acc[e] += __shfl_xor(acc[e], off, 64);

    if (lane == 0) {
        float p[EE]; float m = -1e30f;
#pragma unroll
        for (int e = 0; e < EE; ++e) { p[e] = acc[e] + bg[e]; m = fmaxf(m, p[e]); }
        float s = 0.f;
#pragma unroll
        for (int e = 0; e < EE; ++e) { p[e] = expf(p[e] - m); s += p[e]; }
        float inv = 1.f / s, q = 0.f;
#pragma unroll
        for (int e = 0; e < EE; ++e) { p[e] = 0.99f * p[e] * inv + 0.00125f; q += p[e] * p[e]; }
        ssq[t] = q;
        int i1 = 0;
#pragma unroll
        for (int e = 1; e < EE; ++e) if (p[e] > p[i1]) i1 = e;    // lowest idx on tie
        int i2 = (i1 == 0) ? 1 : 0;
#pragma unroll
        for (int e = 0; e < EE; ++e) if (e != i1 && p[e] > p[i2]) i2 = e;
        tk_pack[t] = i1 | (i2 << 4);
        tk_w[t] = p[i1] / (p[i1] + p[i2]);             // w2 = 1 - w1
    }
}

// ---------------- scatter: per-block LDS histogram + 8 global atomics/block ----------------
__global__ __launch_bounds__(256) void scatter_kernel(const int* __restrict__ tk_pack,
                                                      int* __restrict__ counts,
                                                      int* __restrict__ tok_list,
                                                      int* __restrict__ tk_pos) {
    __shared__ int lcnt[EE];
    __shared__ int gbase[EE];
    int tid = threadIdx.x;
    int t = blockIdx.x * 256 + tid;
    if (tid < EE) lcnt[tid] = 0;
    __syncthreads();
    int pk = tk_pack[t];
    int i1 = pk & 15, i2 = pk >> 4;
    int p1 = atomicAdd(&lcnt[i1], 1);                  // LDS atomics: cheap
    int p2 = atomicAdd(&lcnt[i2], 1);
    __syncthreads();
    if (tid < EE) gbase[tid] = atomicAdd(&counts[tid], lcnt[tid]);   // 8 global atomics/block
    __syncthreads();
    int q1 = gbase[i1] + p1, q2 = gbase[i2] + p2;      // positions within expert lists
    tok_list[i1 * BT + q1] = t;
    tok_list[i2 * BT + q2] = t;
    tk_pos[t] = q1 | (q2 << 16);                       // q < 8192 fits 16 bits
}

__global__ void offsets_kernel(const int* __restrict__ counts, int* __restrict__ offs) {
    if (threadIdx.x == 0) {
        int a = 0;
        for (int e = 0; e < EE; ++e) { offs[e] = a; a += counts[e]; }
        offs[EE] = a;
    }
}

// ---------------- GEMM1: h = gelu(x_gathered @ W1 + b1) -> bf16 hbuf ----------------
// 1-D grid, expert = blockIdx % 8 -> all blocks of expert e land on XCD e (W1T[e] L2-resident)
__global__ __launch_bounds__(256) void gemm1_kernel(
        const unsigned short* __restrict__ xbf, const unsigned short* __restrict__ W1T,
        const float* __restrict__ b1, const int* __restrict__ counts,
        const int* __restrict__ offs, const int* __restrict__ tok_list,
        unsigned short* __restrict__ hbuf) {
    int p = blockIdx.x;
    int e = p & 7;
    int j = p >> 3;
    int h0 = (j & 15) * 128;
    int m0 = (j >> 4) * 128;
    int cnt = counts[e];
    if (m0 >= cnt) return;
    int base = offs[e];

    __shared__ __align__(16) unsigned short As[128 * 32];
    __shared__ __align__(16) unsigned short Bs[128 * 32];

    int tid = threadIdx.x, l = tid & 63, w = tid >> 6;
    int wr = w >> 1, wc = w & 1;

    int rs0 = w * 32 + (l >> 2);
    int rs1 = rs0 + 16;
    int g0  = (l & 3) ^ ((rs0 >> 1) & 3);      // swizzled source granule
    int g1  = (l & 3) ^ ((rs1 >> 1) & 3);
    int ra0 = m0 + rs0; if (ra0 >= cnt) ra0 = cnt - 1;
    int ra1 = m0 + rs1; if (ra1 >= cnt) ra1 = cnt - 1;
    const unsigned short* pa0 = xbf + (size_t)tok_list[e * BT + ra0] * DD + g0 * 8;
    const unsigned short* pa1 = xbf + (size_t)tok_list[e * BT + ra1] * DD + g1 * 8;
    const unsigned short* pb0 = W1T + ((size_t)e * HH + h0 + rs0) * DD + g0 * 8;
    const unsigned short* pb1 = W1T + ((size_t)e * HH + h0 + rs1) * DD + g1 * 8;
    unsigned short* lA = As + w * 1024;
    unsigned short* lB = Bs + w * 1024;

    int slot = (l >> 4) ^ ((l >> 1) & 3);      // swizzled read granule
    int arow = wr * 64 + (l & 15);
    int brow = wc * 64 + (l & 15);

    f32x4 acc[4][4];
#pragma unroll
    for (int i = 0; i < 4; ++i)
#pragma unroll
        for (int jj = 0; jj < 4; ++jj) acc[i][jj] = (f32x4){0.f, 0.f, 0.f, 0.f};

    for (int ks = 0; ks < DD / 32; ++ks) {
        __syncthreads();
        gload16(pa0, lA);
        gload16(pa1, lA + 512);
        gload16(pb0, lB);
        gload16(pb1, lB + 512);
        pa0 += 32; pa1 += 32; pb0 += 32; pb1 += 32;
        __syncthreads();

        bf16x8 af[4], bfr[4];
#pragma unroll
        for (int f = 0; f < 4; ++f) {
            af[f]  = *(const bf16x8*)&As[(arow + f * 16) * 32 + slot * 8];
            bfr[f] = *(const bf16x8*)&Bs[(brow + f * 16) * 32 + slot * 8];
        }
#pragma unroll
        for (int fm = 0; fm < 4; ++fm)
#pragma unroll
            for (int fn = 0; fn < 4; ++fn)
                acc[fm][fn] = __builtin_amdgcn_mfma_f32_16x16x32_bf16(af[fm], bfr[fn], acc[fm][fn], 0, 0, 0);
    }

    const float* b1e = b1 + e * HH;
#pragma unroll
    for (int fm = 0; fm < 4; ++fm) {
#pragma unroll
        for (int jj = 0; jj < 4; ++jj) {
            int r = m0 + wr * 64 + fm * 16 + (l >> 4) * 4 + jj;
            if (r >= cnt) continue;
            size_t rb = (size_t)(base + r) * HH;
#pragma unroll
            for (int fn = 0; fn < 4; ++fn) {
                int h = h0 + wc * 64 + fn * 16 + (l & 15);
                float v = acc[fm][fn][jj] + b1e[h];
                v = 0.5f * v * (1.f + erff(v * 0.70710678118654752f));   // exact gelu
                hbuf[rb + h] = f2bf(v);
            }
        }
    }
}

// ---------------- GEMM2: ybuf = (h @ W2 + b2) in expert-row order, bf16, no atomics ----------------
__global__ __launch_bounds__(256) void gemm2_kernel(
        const unsigned short* __restrict__ hbuf, const unsigned short* __restrict__ W2T,
        const float* __restrict__ b2, const int* __restrict__ counts, const int* __restrict__ offs,
        unsigned short* __restrict__ ybuf) {
    int p = blockIdx.x;
    int e = p & 7;
    int j = p >> 3;
    int d0 = (j & 7) * 128;
    int m0 = (j >> 3) * 128;
    int cnt = counts[e];
    if (m0 >= cnt) return;
    int base = offs[e];

    __shared__ __align__(16) unsigned short As[128 * 32];
    __shared__ __align__(16) unsigned short Bs[128 * 32];

    int tid = threadIdx.x, l = tid & 63, w = tid >> 6;
    int wr = w >> 1, wc = w & 1;

    int rs0 = w * 32 + (l >> 2);
    int rs1 = rs0 + 16;
    int g0  = (l & 3) ^ ((rs0 >> 1) & 3);
    int g1  = (l & 3) ^ ((rs1 >> 1) & 3);
    int ra0 = m0 + rs0; if (ra0 >= cnt) ra0 = cnt - 1;
    int ra1 = m0 + rs1; if (ra1 >= cnt) ra1 = cnt - 1;
    const unsigned short* pa0 = hbuf + (size_t)(base + ra0) * HH + g0 * 8;
    const unsigned short* pa1 = hbuf + (size_t)(base + ra1) * HH + g1 * 8;
    const unsigned short* pb0 = W2T + ((size_t)e * DD + d0 + rs0) * HH + g0 * 8;
    const unsigned short* pb1 = W2T + ((size_t)e * DD + d0 + rs1) * HH + g1 * 8;
    unsigned short* lA = As + w * 1024;
    unsigned short* lB = Bs + w * 1024;

    int slot = (l >> 4) ^ ((l >> 1) & 3);
    int arow = wr * 64 + (l & 15);
    int brow = wc * 64 + (l & 15);

    f32x4 acc[4][4];
#pragma unroll
    for (int i = 0; i < 4; ++i)
#pragma unroll
        for (int jj = 0; jj < 4; ++jj) acc[i][jj] = (f32x4){0.f, 0.f, 0.f, 0.f};

    for (int ks = 0; ks < HH / 32; ++ks) {
        __syncthreads();
        gload16(pa0, lA);
        gload16(pa1, lA + 512);
        gload16(pb0, lB);
        gload16(pb1, lB + 512);
        pa0 += 32; pa1 += 32; pb0 += 32; pb1 += 32;
        __syncthreads();

        bf16x8 af[4], bfr[4];
#pragma unroll
        for (int f = 0; f < 4; ++f) {
            af[f]  = *(const bf16x8*)&As[(arow + f * 16) * 32 + slot * 8];
            bfr[f] = *(const bf16x8*)&Bs[(brow + f * 16) * 32 + slot * 8];
        }
#pragma unroll
        for (int fm = 0; fm < 4; ++fm)
#pragma unroll
            for (int fn = 0; fn < 4; ++fn)
                acc[fm][fn] = __builtin_amdgcn_mfma_f32_16x16x32_bf16(af[fm], bfr[fn], acc[fm][fn], 0, 0, 0);
    }

    const float* b2e = b2 + e * DD;
#pragma unroll
    for (int fm = 0; fm < 4; ++fm) {
#pragma unroll
        for (int jj = 0; jj < 4; ++jj) {
            int r = m0 + wr * 64 + fm * 16 + (l >> 4) * 4 + jj;
            if (r >= cnt) continue;
            size_t rb = (size_t)(base + r) * DD;
#pragma unroll
            for (int fn = 0; fn < 4; ++fn) {
                int d = d0 + wc * 64 + fn * 16 + (l & 15);
                ybuf[rb + d] = f2bf(acc[fm][fn][jj] + b2e[d]);   // plain store, no RMW
            }
        }
    }
}

// ---------------- combine: out[t] = w1*y[row1] + (1-w1)*y[row2] ----------------
__global__ __launch_bounds__(256) void combine_kernel(
        const unsigned short* __restrict__ ybuf, const int* __restrict__ offs,
        const int* __restrict__ tk_pack, const float* __restrict__ tk_w,
        const int* __restrict__ tk_pos, float* __restrict__ out) {
    int tid = threadIdx.x;
    int t  = blockIdx.x * 2 + (tid >> 7);              // 2 tokens per block
    int lt = tid & 127;                                // 8 floats per thread
    int pk  = tk_pack[t];
    int pos = tk_pos[t];
    float w1 = tk_w[t], w2 = 1.f - w1;
    int r1 = offs[pk & 15] + (pos & 0xffff);
    int r2 = offs[pk >> 4] + (pos >> 16);
    ushort4 a0 = ((const ushort4*)(ybuf + (size_t)r1 * DD))[lt * 2];
    ushort4 a1 = ((const ushort4*)(ybuf + (size_t)r1 * DD))[lt * 2 + 1];
    ushort4 b0 = ((const ushort4*)(ybuf + (size_t)r2 * DD))[lt * 2];
    ushort4 b1 = ((const ushort4*)(ybuf + (size_t)r2 * DD))[lt * 2 + 1];
    float4 o0 = { w1 * bf2f(a0.x) + w2 * bf2f(b0.x), w1 * bf2f(a0.y) + w2 * bf2f(b0.y),
                  w1 * bf2f(a0.z) + w2 * bf2f(b0.z), w1 * bf2f(a0.w) + w2 * bf2f(b0.w) };
    float4 o1 = { w1 * bf2f(a1.x) + w2 * bf2f(b1.x), w1 * bf2f(a1.y) + w2 * bf2f(b1.y),
                  w1 * bf2f(a1.z) + w2 * bf2f(b1.z), w1 * bf2f(a1.w) + w2 * bf2f(b1.w) };
    float4* orow = (float4*)(out + (size_t)t * DD);
    orow[lt * 2]     = o0;
    orow[lt * 2 + 1] = o1;
}

// ---------------- aux = mean(sum probs^2) * E ----------------
__global__ void aux_kernel(const float* __restrict__ ssq, float* __restrict__ out_aux) {
    __shared__ float red[4];
    float s = 0.f;
    for (int i = threadIdx.x; i < BT; i += 256) s += ssq[i];
#pragma unroll
    for (int off = 32; off; off >>= 1) s += __shfl_xor(s, off, 64);
    if ((threadIdx.x & 63) == 0) red[threadIdx.x >> 6] = s;
    __syncthreads();
    if (threadIdx.x == 0)
        out_aux[0] = (red[0] + red[1] + red[2] + red[3]) * (float)EE / (float)BT;
}

extern "C" void kernel_launch(void* const* d_in, const int* in_sizes, int n_in,
                              void* d_out, int out_size, void* d_ws, size_t ws_size,
                              hipStream_t stream) {
    const float* x  = (const float*)d_in[0];
    const float* Wg = (const float*)d_in[1];
    const float* bg = (const float*)d_in[2];
    const float* W1 = (const float*)d_in[3];
    const float* b1 = (const float*)d_in[4];
    const float* W2 = (const float*)d_in[5];
    const float* b2 = (const float*)d_in[6];
    float* out = (float*)d_out;

    char* wsb = (char*)d_ws;
    int*   counts  = (int*)wsb;                         // 0 .. 64
    int*   offs    = (int*)(wsb + 64);                  // 64 .. 256
    int*   tok     = (int*)(wsb + 256);                 // 8*8192*4 -> 262400
    float* ssq     = (float*)(wsb + 262400);            // 32 KB -> 295168
    int*   tk_pack = (int*)(wsb + 295168);              // 32 KB -> 327936
    float* tk_w    = (float*)(wsb + 327936);            // 32 KB -> 360704
    int*   tk_pos  = (int*)(wsb + 360704);              // 32 KB -> 393472
    unsigned short* xbf  = (unsigned short*)(wsb + 393472);      // 16 MB -> 17170688
    unsigned short* W1T  = (unsigned short*)(wsb + 17170688);    // 32 MB -> 50725120
    unsigned short* W2T  = (unsigned short*)(wsb + 50725120);    // 32 MB -> 84279552
    unsigned short* hbuf = (unsigned short*)(wsb + 84279552);    // 64 MB -> 151388416
    // ybuf (33.5 MB bf16) overlays xbf+W1T — both dead once gemm1 has run
    unsigned short* ybuf = (unsigned short*)(wsb + 393472);

    hipMemsetAsync(wsb, 0, 64, stream);                 // counts only; out fully written by combine

    cvt_x_kernel<<<BT * DD / (256 * 8), 256, 0, stream>>>(x, xbf);
    transpose_cvt_kernel<<<dim3(HH / 64, DD / 64, EE), 256, 0, stream>>>(W1, W1T, DD, HH);
    transpose_cvt_kernel<<<dim3(DD / 64, HH / 64, EE), 256, 0, stream>>>(W2, W2T, HH, DD);
    gating_kernel<<<BT / 4, 256, 0, stream>>>(x, Wg, bg, tk_pack, tk_w, ssq);
    scatter_kernel<<<BT / 256, 256, 0, stream>>>(tk_pack, counts, tok, tk_pos);
    offsets_kernel<<<1, 64, 0, stream>>>(counts, offs);
    gemm1_kernel<<<8 * 16 * (BT / 128), 256, 0, stream>>>(xbf, W1T, b1, counts, offs, tok, hbuf);
    gemm2_kernel<<<8 * 8 * (BT / 128), 256, 0, stream>>>(hbuf, W2T, b2, counts, offs, ybuf);
    combine_kernel<<<BT / 2, 256, 0, stream>>>(ybuf, offs, tk_pack, tk_w, tk_pos, out);
    aux_kernel<<<1, 256, 0, stream>>>(ssq, out + (size_t)BT * DD);
}

// Round 5
// 297.487 us; speedup vs baseline: 2.3705x; 1.0538x over previous
//
#include <hip/hip_runtime.h>
#include <hip/hip_bf16.h>
#include <cmath>

#define BT 8192      // B*T tokens
#define DD 1024      // model dim
#define EE 8         // experts
#define HH 2048      // hidden

typedef __attribute__((ext_vector_type(8))) short bf16x8;
typedef __attribute__((ext_vector_type(4))) float f32x4;

__device__ __forceinline__ unsigned short f2bf(float f) {
    union { float f; unsigned u; } v; v.f = f;
    unsigned r = v.u + 0x7FFFu + ((v.u >> 16) & 1u);   // RNE
    return (unsigned short)(r >> 16);
}

__device__ __forceinline__ float bf2f(unsigned short s) {
    union { unsigned u; float f; } v; v.u = ((unsigned)s) << 16;
    return v.f;
}

// tanh-form GELU via sigmoid: x * sigmoid(2c(x + 0.044715 x^3)), 2c = 1.5957691216
// max |diff vs exact erf-GELU| ~5e-4; one v_exp_f32 instead of ~27-op erff polynomial
__device__ __forceinline__ float gelu_fast(float x) {
    float z = x * (1.5957691216f + 0.071354816f * x * x);
    return x / (1.f + __expf(-z));
}

// async global->LDS, 16B per lane; LDS dest = wave-uniform base + lane*16
__device__ __forceinline__ void gload16(const void* g, void* l) {
    __builtin_amdgcn_global_load_lds(
        (const __attribute__((address_space(1))) void*)g,
        (__attribute__((address_space(3))) void*)l, 16, 0, 0);
}

// ---------------- prepass: x fp32 -> bf16 ----------------
__global__ __launch_bounds__(256) void cvt_x_kernel(const float* __restrict__ x,
                                                    unsigned short* __restrict__ xbf) {
    int i = blockIdx.x * 256 + threadIdx.x;            // 8 elems per thread
    float4 a = ((const float4*)x)[i * 2];
    float4 b = ((const float4*)x)[i * 2 + 1];
    ushort4 lo = { f2bf(a.x), f2bf(a.y), f2bf(a.z), f2bf(a.w) };
    ushort4 hi = { f2bf(b.x), f2bf(b.y), f2bf(b.z), f2bf(b.w) };
    ((ushort4*)xbf)[i * 2]     = lo;
    ((ushort4*)xbf)[i * 2 + 1] = hi;
}

// ---------------- prepass: W [E][R][C] fp32 -> WT [E][C][R] bf16 ----------------
__global__ __launch_bounds__(256) void transpose_cvt_kernel(const float* __restrict__ in,
                                                            unsigned short* __restrict__ out,
                                                            int R, int C) {
    __shared__ unsigned short t[64][66];               // pad 2 shorts: conflict-free
    int e  = blockIdx.z;
    int r0 = blockIdx.y * 64, c0 = blockIdx.x * 64;
    int tid = threadIdx.x;
    int ci = tid & 63, ri = tid >> 6;
    const float* src = in + ((size_t)e * R + r0) * C + c0;
#pragma unroll
    for (int j = 0; j < 16; ++j) {
        int r = ri + j * 4;
        t[ci][r] = f2bf(src[(size_t)r * C + ci]);      // coalesced read along C
    }
    __syncthreads();
    int r2 = (tid & 15) * 4, c2 = tid >> 4;            // c2 in 0..15
    unsigned short* dst = out + ((size_t)e * C + c0) * R + r0;
#pragma unroll
    for (int j = 0; j < 4; ++j) {
        int c = c2 + j * 16;
        ushort4 v = { t[c][r2], t[c][r2 + 1], t[c][r2 + 2], t[c][r2 + 3] };
        *(ushort4*)&dst[(size_t)c * R + r2] = v;       // coalesced write along R
    }
}

// ---------------- gating: logits, unimix softmax, top-2 — NO atomics ----------------
__global__ void gating_kernel(const float* __restrict__ x, const float* __restrict__ Wg,
                              const float* __restrict__ bg, int* __restrict__ tk_pack,
                              float* __restrict__ tk_w, float* __restrict__ ssq) {
    int lane = threadIdx.x & 63;
    int wid  = threadIdx.x >> 6;
    int t = blockIdx.x * 4 + wid;           // one wave per token
    const float* xr = x + (size_t)t * DD;
    float acc[EE];
#pragma unroll
    for (int e = 0; e < EE; ++e) acc[e] = 0.f;
    for (int d = lane; d < DD; d += 64) {
        float xv = xr[d];
        const float* wr = Wg + d * EE;
#pragma unroll
        for (int e = 0; e < EE; ++e) acc[e] += xv * wr[e];
    }
#pragma unroll
    for (int off = 32; off; off >>= 1)
#pragma unroll
        for (int e = 0; e < EE; ++e) acc[e] += __shfl_xor(acc[e], off, 64);

    if (lane == 0) {
        float p[EE]; float m = -1e30f;
#pragma unroll
        for (int e = 0; e < EE; ++e) { p[e] = acc[e] + bg[e]; m = fmaxf(m, p[e]); }
        float s = 0.f;
#pragma unroll
        for (int e = 0; e < EE; ++e) { p[e] = expf(p[e] - m); s += p[e]; }
        float inv = 1.f / s, q = 0.f;
#pragma unroll
        for (int e = 0; e < EE; ++e) { p[e] = 0.99f * p[e] * inv + 0.00125f; q += p[e] * p[e]; }
        ssq[t] = q;
        int i1 = 0;
#pragma unroll
        for (int e = 1; e < EE; ++e) if (p[e] > p[i1]) i1 = e;    // lowest idx on tie
        int i2 = (i1 == 0) ? 1 : 0;
#pragma unroll
        for (int e = 0; e < EE; ++e) if (e != i1 && p[e] > p[i2]) i2 = e;
        tk_pack[t] = i1 | (i2 << 4);
        tk_w[t] = p[i1] / (p[i1] + p[i2]);             // w2 = 1 - w1
    }
}

// ---------------- scatter: per-block LDS histogram + 8 global atomics/block ----------------
__global__ __launch_bounds__(256) void scatter_kernel(const int* __restrict__ tk_pack,
                                                      int* __restrict__ counts,
                                                      int* __restrict__ tok_list,
                                                      int* __restrict__ tk_pos) {
    __shared__ int lcnt[EE];
    __shared__ int gbase[EE];
    int tid = threadIdx.x;
    int t = blockIdx.x * 256 + tid;
    if (tid < EE) lcnt[tid] = 0;
    __syncthreads();
    int pk = tk_pack[t];
    int i1 = pk & 15, i2 = pk >> 4;
    int p1 = atomicAdd(&lcnt[i1], 1);                  // LDS atomics: cheap
    int p2 = atomicAdd(&lcnt[i2], 1);
    __syncthreads();
    if (tid < EE) gbase[tid] = atomicAdd(&counts[tid], lcnt[tid]);   // 8 global atomics/block
    __syncthreads();
    int q1 = gbase[i1] + p1, q2 = gbase[i2] + p2;      // positions within expert lists
    tok_list[i1 * BT + q1] = t;
    tok_list[i2 * BT + q2] = t;
    tk_pos[t] = q1 | (q2 << 16);                       // q < 8192 fits 16 bits
}

__global__ void offsets_kernel(const int* __restrict__ counts, int* __restrict__ offs) {
    if (threadIdx.x == 0) {
        int a = 0;
        for (int e = 0; e < EE; ++e) { offs[e] = a; a += counts[e]; }
        offs[EE] = a;
    }
}

// ---------------- GEMM1: h = gelu(x_gathered @ W1 + b1) -> bf16 hbuf ----------------
// 1-D grid, expert = blockIdx % 8 -> all blocks of expert e land on XCD e (W1T[e] L2-resident)
// MFMA operands SWAPPED: D row-index = h fragment -> each lane holds 4 consecutive h values
__global__ __launch_bounds__(256) void gemm1_kernel(
        const unsigned short* __restrict__ xbf, const unsigned short* __restrict__ W1T,
        const float* __restrict__ b1, const int* __restrict__ counts,
        const int* __restrict__ offs, const int* __restrict__ tok_list,
        unsigned short* __restrict__ hbuf) {
    int p = blockIdx.x;
    int e = p & 7;
    int j = p >> 3;
    int h0 = (j & 15) * 128;
    int m0 = (j >> 4) * 128;
    int cnt = counts[e];
    if (m0 >= cnt) return;
    int base = offs[e];

    __shared__ __align__(16) unsigned short As[128 * 32];
    __shared__ __align__(16) unsigned short Bs[128 * 32];

    int tid = threadIdx.x, l = tid & 63, w = tid >> 6;
    int wr = w >> 1, wc = w & 1;

    int rs0 = w * 32 + (l >> 2);
    int rs1 = rs0 + 16;
    int g0  = (l & 3) ^ ((rs0 >> 1) & 3);      // swizzled source granule
    int g1  = (l & 3) ^ ((rs1 >> 1) & 3);
    int ra0 = m0 + rs0; if (ra0 >= cnt) ra0 = cnt - 1;
    int ra1 = m0 + rs1; if (ra1 >= cnt) ra1 = cnt - 1;
    const unsigned short* pa0 = xbf + (size_t)tok_list[e * BT + ra0] * DD + g0 * 8;
    const unsigned short* pa1 = xbf + (size_t)tok_list[e * BT + ra1] * DD + g1 * 8;
    const unsigned short* pb0 = W1T + ((size_t)e * HH + h0 + rs0) * DD + g0 * 8;
    const unsigned short* pb1 = W1T + ((size_t)e * HH + h0 + rs1) * DD + g1 * 8;
    unsigned short* lA = As + w * 1024;
    unsigned short* lB = Bs + w * 1024;

    int slot = (l >> 4) ^ ((l >> 1) & 3);      // swizzled read granule
    int arow = wr * 64 + (l & 15);
    int brow = wc * 64 + (l & 15);

    f32x4 acc[4][4];
#pragma unroll
    for (int i = 0; i < 4; ++i)
#pragma unroll
        for (int jj = 0; jj < 4; ++jj) acc[i][jj] = (f32x4){0.f, 0.f, 0.f, 0.f};

    for (int ks = 0; ks < DD / 32; ++ks) {
        __syncthreads();
        gload16(pa0, lA);
        gload16(pa1, lA + 512);
        gload16(pb0, lB);
        gload16(pb1, lB + 512);
        pa0 += 32; pa1 += 32; pb0 += 32; pb1 += 32;
        __syncthreads();

        bf16x8 af[4], bfr[4];
#pragma unroll
        for (int f = 0; f < 4; ++f) {
            af[f]  = *(const bf16x8*)&As[(arow + f * 16) * 32 + slot * 8];
            bfr[f] = *(const bf16x8*)&Bs[(brow + f * 16) * 32 + slot * 8];
        }
#pragma unroll
        for (int fm = 0; fm < 4; ++fm)
#pragma unroll
            for (int fn = 0; fn < 4; ++fn)   // swapped: D[h][token]
                acc[fm][fn] = __builtin_amdgcn_mfma_f32_16x16x32_bf16(bfr[fn], af[fm], acc[fm][fn], 0, 0, 0);
    }

    // epilogue: lane holds 4 consecutive h (j=0..3) for token col = l&15
    const float* b1e = b1 + e * HH;
#pragma unroll
    for (int fm = 0; fm < 4; ++fm) {
        int r = m0 + wr * 64 + fm * 16 + (l & 15);
        if (r >= cnt) continue;
        unsigned short* hrow = hbuf + (size_t)(base + r) * HH;
#pragma unroll
        for (int fn = 0; fn < 4; ++fn) {
            int hb = h0 + wc * 64 + fn * 16 + (l >> 4) * 4;
            float4 bb = *(const float4*)&b1e[hb];
            f32x4 a = acc[fm][fn];
            ushort4 pk = { f2bf(gelu_fast(a[0] + bb.x)), f2bf(gelu_fast(a[1] + bb.y)),
                           f2bf(gelu_fast(a[2] + bb.z)), f2bf(gelu_fast(a[3] + bb.w)) };
            *(ushort4*)&hrow[hb] = pk;
        }
    }
}

// ---------------- GEMM2: ybuf = (h @ W2 + b2) in expert-row order, bf16, no atomics ----------------
__global__ __launch_bounds__(256) void gemm2_kernel(
        const unsigned short* __restrict__ hbuf, const unsigned short* __restrict__ W2T,
        const float* __restrict__ b2, const int* __restrict__ counts, const int* __restrict__ offs,
        unsigned short* __restrict__ ybuf) {
    int p = blockIdx.x;
    int e = p & 7;
    int j = p >> 3;
    int d0 = (j & 7) * 128;
    int m0 = (j >> 3) * 128;
    int cnt = counts[e];
    if (m0 >= cnt) return;
    int base = offs[e];

    __shared__ __align__(16) unsigned short As[128 * 32];
    __shared__ __align__(16) unsigned short Bs[128 * 32];

    int tid = threadIdx.x, l = tid & 63, w = tid >> 6;
    int wr = w >> 1, wc = w & 1;

    int rs0 = w * 32 + (l >> 2);
    int rs1 = rs0 + 16;
    int g0  = (l & 3) ^ ((rs0 >> 1) & 3);
    int g1  = (l & 3) ^ ((rs1 >> 1) & 3);
    int ra0 = m0 + rs0; if (ra0 >= cnt) ra0 = cnt - 1;
    int ra1 = m0 + rs1; if (ra1 >= cnt) ra1 = cnt - 1;
    const unsigned short* pa0 = hbuf + (size_t)(base + ra0) * HH + g0 * 8;
    const unsigned short* pa1 = hbuf + (size_t)(base + ra1) * HH + g1 * 8;
    const unsigned short* pb0 = W2T + ((size_t)e * DD + d0 + rs0) * HH + g0 * 8;
    const unsigned short* pb1 = W2T + ((size_t)e * DD + d0 + rs1) * HH + g1 * 8;
    unsigned short* lA = As + w * 1024;
    unsigned short* lB = Bs + w * 1024;

    int slot = (l >> 4) ^ ((l >> 1) & 3);
    int arow = wr * 64 + (l & 15);
    int brow = wc * 64 + (l & 15);

    f32x4 acc[4][4];
#pragma unroll
    for (int i = 0; i < 4; ++i)
#pragma unroll
        for (int jj = 0; jj < 4; ++jj) acc[i][jj] = (f32x4){0.f, 0.f, 0.f, 0.f};

    for (int ks = 0; ks < HH / 32; ++ks) {
        __syncthreads();
        gload16(pa0, lA);
        gload16(pa1, lA + 512);
        gload16(pb0, lB);
        gload16(pb1, lB + 512);
        pa0 += 32; pa1 += 32; pb0 += 32; pb1 += 32;
        __syncthreads();

        bf16x8 af[4], bfr[4];
#pragma unroll
        for (int f = 0; f < 4; ++f) {
            af[f]  = *(const bf16x8*)&As[(arow + f * 16) * 32 + slot * 8];
            bfr[f] = *(const bf16x8*)&Bs[(brow + f * 16) * 32 + slot * 8];
        }
#pragma unroll
        for (int fm = 0; fm < 4; ++fm)
#pragma unroll
            for (int fn = 0; fn < 4; ++fn)   // swapped: D[d][token]
                acc[fm][fn] = __builtin_amdgcn_mfma_f32_16x16x32_bf16(bfr[fn], af[fm], acc[fm][fn], 0, 0, 0);
    }

    const float* b2e = b2 + e * DD;
#pragma unroll
    for (int fm = 0; fm < 4; ++fm) {
        int r = m0 + wr * 64 + fm * 16 + (l & 15);
        if (r >= cnt) continue;
        unsigned short* yrow = ybuf + (size_t)(base + r) * DD;
#pragma unroll
        for (int fn = 0; fn < 4; ++fn) {
            int db = d0 + wc * 64 + fn * 16 + (l >> 4) * 4;
            float4 bb = *(const float4*)&b2e[db];
            f32x4 a = acc[fm][fn];
            ushort4 pk = { f2bf(a[0] + bb.x), f2bf(a[1] + bb.y),
                           f2bf(a[2] + bb.z), f2bf(a[3] + bb.w) };
            *(ushort4*)&yrow[db] = pk;
        }
    }
}

// ---------------- combine: out[t] = w1*y[row1] + (1-w1)*y[row2] ----------------
__global__ __launch_bounds__(256) void combine_kernel(
        const unsigned short* __restrict__ ybuf, const int* __restrict__ offs,
        const int* __restrict__ tk_pack, const float* __restrict__ tk_w,
        const int* __restrict__ tk_pos, float* __restrict__ out) {
    int tid = threadIdx.x;
    int t  = blockIdx.x * 2 + (tid >> 7);              // 2 tokens per block
    int lt = tid & 127;                                // 8 floats per thread
    int pk  = tk_pack[t];
    int pos = tk_pos[t];
    float w1 = tk_w[t], w2 = 1.f - w1;
    int r1 = offs[pk & 15] + (pos & 0xffff);
    int r2 = offs[pk >> 4] + (pos >> 16);
    ushort4 a0 = ((const ushort4*)(ybuf + (size_t)r1 * DD))[lt * 2];
    ushort4 a1 = ((const ushort4*)(ybuf + (size_t)r1 * DD))[lt * 2 + 1];
    ushort4 b0 = ((const ushort4*)(ybuf + (size_t)r2 * DD))[lt * 2];
    ushort4 b1 = ((const ushort4*)(ybuf + (size_t)r2 * DD))[lt * 2 + 1];
    float4 o0 = { w1 * bf2f(a0.x) + w2 * bf2f(b0.x), w1 * bf2f(a0.y) + w2 * bf2f(b0.y),
                  w1 * bf2f(a0.z) + w2 * bf2f(b0.z), w1 * bf2f(a0.w) + w2 * bf2f(b0.w) };
    float4 o1 = { w1 * bf2f(a1.x) + w2 * bf2f(b1.x), w1 * bf2f(a1.y) + w2 * bf2f(b1.y),
                  w1 * bf2f(a1.z) + w2 * bf2f(b1.z), w1 * bf2f(a1.w) + w2 * bf2f(b1.w) };
    float4* orow = (float4*)(out + (size_t)t * DD);
    orow[lt * 2]     = o0;
    orow[lt * 2 + 1] = o1;
}

// ---------------- aux = mean(sum probs^2) * E ----------------
__global__ void aux_kernel(const float* __restrict__ ssq, float* __restrict__ out_aux) {
    __shared__ float red[4];
    float s = 0.f;
    for (int i = threadIdx.x; i < BT; i += 256) s += ssq[i];
#pragma unroll
    for (int off = 32; off; off >>= 1) s += __shfl_xor(s, off, 64);
    if ((threadIdx.x & 63) == 0) red[threadIdx.x >> 6] = s;
    __syncthreads();
    if (threadIdx.x == 0)
        out_aux[0] = (red[0] + red[1] + red[2] + red[3]) * (float)EE / (float)BT;
}

extern "C" void kernel_launch(void* const* d_in, const int* in_sizes, int n_in,
                              void* d_out, int out_size, void* d_ws, size_t ws_size,
                              hipStream_t stream) {
    const float* x  = (const float*)d_in[0];
    const float* Wg = (const float*)d_in[1];
    const float* bg = (const float*)d_in[2];
    const float* W1 = (const float*)d_in[3];
    const float* b1 = (const float*)d_in[4];
    const float* W2 = (const float*)d_in[5];
    const float* b2 = (const float*)d_in[6];
    float* out = (float*)d_out;

    char* wsb = (char*)d_ws;
    int*   counts  = (int*)wsb;                         // 0 .. 64
    int*   offs    = (int*)(wsb + 64);                  // 64 .. 256
    int*   tok     = (int*)(wsb + 256);                 // 8*8192*4 -> 262400
    float* ssq     = (float*)(wsb + 262400);            // 32 KB -> 295168
    int*   tk_pack = (int*)(wsb + 295168);              // 32 KB -> 327936
    float* tk_w    = (float*)(wsb + 327936);            // 32 KB -> 360704
    int*   tk_pos  = (int*)(wsb + 360704);              // 32 KB -> 393472
    unsigned short* xbf  = (unsigned short*)(wsb + 393472);      // 16 MB -> 17170688
    unsigned short* W1T  = (unsigned short*)(wsb + 17170688);    // 32 MB -> 50725120
    unsigned short* W2T  = (unsigned short*)(wsb + 50725120);    // 32 MB -> 84279552
    unsigned short* hbuf = (unsigned short*)(wsb + 84279552);    // 64 MB -> 151388416
    // ybuf (33.5 MB bf16) overlays xbf+W1T — both dead once gemm1 has run
    unsigned short* ybuf = (unsigned short*)(wsb + 393472);

    hipMemsetAsync(wsb, 0, 64, stream);                 // counts only; out fully written by combine

    cvt_x_kernel<<<BT * DD / (256 * 8), 256, 0, stream>>>(x, xbf);
    transpose_cvt_kernel<<<dim3(HH / 64, DD / 64, EE), 256, 0, stream>>>(W1, W1T, DD, HH);
    transpose_cvt_kernel<<<dim3(DD / 64, HH / 64, EE), 256, 0, stream>>>(W2, W2T, HH, DD);
    gating_kernel<<<BT / 4, 256, 0, stream>>>(x, Wg, bg, tk_pack, tk_w, ssq);
    scatter_kernel<<<BT / 256, 256, 0, stream>>>(tk_pack, counts, tok, tk_pos);
    offsets_kernel<<<1, 64, 0, stream>>>(counts, offs);
    gemm1_kernel<<<8 * 16 * (BT / 128), 256, 0, stream>>>(xbf, W1T, b1, counts, offs, tok, hbuf);
    gemm2_kernel<<<8 * 8 * (BT / 128), 256, 0, stream>>>(hbuf, W2T, b2, counts, offs, ybuf);
    combine_kernel<<<BT / 2, 256, 0, stream>>>(ybuf, offs, tk_pack, tk_w, tk_pos, out);
    aux_kernel<<<1, 256, 0, stream>>>(ssq, out + (size_t)BT * DD);
}